// Round 11
// baseline (632.051 us; speedup 1.0000x reference)
//
#include <hip/hip_runtime.h>
#include <math.h>

#define BTOT   32768
#define LAT    128
#define H      17
#define G4     68      // 4*H
#define TSTEPS 50
#define NPR    102     // projection rows: 68 (W_ih) + 17 (W_h0) + 17 (W_c0)
#define WQ     32      // k-quarter width (floats)
#define WPAD   36      // Wbuf row stride; + XOR swizzle below -> worst 2-way (free)

#define NW     8              // waves per block
#define RPW    3              // rows per wave (51 active lanes of 64)
#define RPB    (NW * RPW)     // 24 rows per block
#define TPB    (NW * 64)      // 512 threads

// R10 lesson: stride 36 alone is 3-way conflicted (8*36 ≡ 0 mod 32, 16.9M cyc).
// XOR bit 2 with (row>>3)&1: rows j/j+8 get different offsets; only j/j+16
// still alias = 2-way = free (m136).
#define WSWZ(row, c4) ((c4) ^ ((((row) >> 3) & 1) << 2))

// fast gates: f32 only (R9: recurrence amplifies per-step error ~1e3x -> f16 fails).
__device__ __forceinline__ float fsigmoid(float x) {
    float e = __expf(-x);
    return __builtin_amdgcn_rcpf(1.0f + e);
}
// tanh(x) = 1 - 2*rcp(exp(2x)+1); +inf -> 1, -inf -> -1, no divide.
__device__ __forceinline__ float ftanhf(float x) {
    float e = __expf(2.0f * x);
    float t = __builtin_amdgcn_rcpf(e + 1.0f);
    return fmaf(-2.0f, t, 1.0f);
}

#define FMAC(acc, w, h) asm("v_fmac_f32 %0, %1, %2" : "+v"(acc) : "v"(w), "v"(h))

__global__ __launch_bounds__(TPB, 5)
void lstm_fused(const float* __restrict__ x,
                const float* __restrict__ W_h0, const float* __restrict__ b_h0,
                const float* __restrict__ W_c0, const float* __restrict__ b_c0,
                const float* __restrict__ W_ih, const float* __restrict__ W_hh,
                const float* __restrict__ b_ih, const float* __restrict__ b_hh,
                float* __restrict__ out)
{
    __shared__ float x_tile[RPB][132];      // 12.7 KB
    __shared__ float Wbuf[NPR][WPAD];       // 14.7 KB (one k-quarter, swizzled)
    __shared__ float Wl[G4 * H];            //  4.6 KB (W_hh f32)
    __shared__ float hbuf[NW][RPW][20];     //  1.9 KB (wave-private h rows)

    const int t    = threadIdx.x;
    const int w    = t >> 6;
    const int lane = t & 63;
    const bool active = lane < RPW * H;       // 51
    const int rl = active ? (lane / H) : 0;   // 0..2
    const int j  = active ? (lane % H) : 0;   // 0..16
    const int r  = w * RPW + rl;              // 0..23
    const int grow0 = blockIdx.x * RPB;
    int grow = grow0 + r;
    const bool valid = active && (grow < BTOT);
    if (grow >= BTOT) grow = BTOT - 1;

    // ---- stage x tile (rows clamped) + W_hh; all 512 threads ----
    for (int i = t; i < RPB * 32; i += TPB) {              // 32 float4 per row
        int rr = i >> 5, c = i & 31;
        int gr = grow0 + rr; if (gr >= BTOT) gr = BTOT - 1;
        *(float4*)&x_tile[rr][c * 4] = ((const float4*)(x + (size_t)gr * LAT))[c];
    }
    for (int i = t; i < G4 * H; i += TPB) Wl[i] = W_hh[i];

    // ---- phase 1: projections in FOUR k-quarters of 32 (LDS diet, R10) ----
    float acc[6] = {0.f, 0.f, 0.f, 0.f, 0.f, 0.f};         // i,f,g,o, h0, c0
    const int rows6[6] = { j, 17 + j, 34 + j, 51 + j, 68 + j, 85 + j };
    for (int qh = 0; qh < 4; ++qh) {
        __syncthreads();  // qh=0: x_tile/Wl ready; else WAR on Wbuf
        for (int i = t; i < NPR * 8; i += TPB) {           // 8 float4 per quarter-row
            int row = i >> 3, c4 = (i & 7) * 4;
            const float* src = (row < G4) ? (W_ih + row * LAT)
                             : (row < 85) ? (W_h0 + (row - G4) * LAT)
                                          : (W_c0 + (row - 85) * LAT);
            *(float4*)&Wbuf[row][WSWZ(row, c4)] = *(const float4*)(src + qh * WQ + c4);
        }
        __syncthreads();  // quarter ready

        for (int kb = 0; kb < 8; ++kb) {
            float4 xv = *(const float4*)&x_tile[r][qh * WQ + kb * 4];
#pragma unroll
            for (int s = 0; s < 6; ++s) {
                const int row = rows6[s];
                float4 wv = *(const float4*)&Wbuf[row][WSWZ(row, kb * 4)];
                acc[s] = fmaf(xv.x, wv.x, acc[s]);
                acc[s] = fmaf(xv.y, wv.y, acc[s]);
                acc[s] = fmaf(xv.z, wv.z, acc[s]);
                acc[s] = fmaf(xv.w, wv.w, acc[s]);
            }
        }
    }

    const float xgi = acc[0] + b_ih[j]      + b_hh[j];
    const float xgf = acc[1] + b_ih[17 + j] + b_hh[17 + j];
    const float xgg = acc[2] + b_ih[34 + j] + b_hh[34 + j];
    const float xgo = acc[3] + b_ih[51 + j] + b_hh[51 + j];
    float h = acc[4] + b_h0[j];
    float c = acc[5] + b_c0[j];

    // ---- W_hh rows for gates i,f,g,o of element j -> registers ----
    float Wi[H], Wf[H], Wg[H], Wo[H];
#pragma unroll
    for (int k = 0; k < H; ++k) {
        Wi[k] = Wl[(0 * H + j) * H + k];
        Wf[k] = Wl[(1 * H + j) * H + k];
        Wg[k] = Wl[(2 * H + j) * H + k];
        Wo[k] = Wl[(3 * H + j) * H + k];
        asm volatile("" : "+v"(Wi[k]), "+v"(Wf[k]), "+v"(Wg[k]), "+v"(Wo[k]));
    }

    // ---- DEPHASE: break wave phase-lock so co-resident waves' LDS windows
    // overlap neighbors' VALU windows (theory: aligned exchange stalls are the
    // 2x gap between 75us issue floor and 153us measured). One-time cost.
    {
        const int stag = (((w >> 2) & 1) << 1) | (blockIdx.x & 1);  // 0..3
        switch (stag) {
            case 1: __builtin_amdgcn_s_sleep(8);  break;   // ~512 cyc
            case 2: __builtin_amdgcn_s_sleep(16); break;   // ~1024 cyc
            case 3: __builtin_amdgcn_s_sleep(24); break;   // ~1536 cyc
            default: break;
        }
    }

    // ---- phase 2: 50-step recurrence, NO barriers (rows are wave-local) ----
    // Output store delayed one step so it issues inside the LDS window.
    float* orow = out + (size_t)grow * (TSTEPS * H) + j;
    for (int tt = 0; tt < TSTEPS; ++tt) {
        if (active) hbuf[w][rl][j] = h;
        if (valid && tt > 0) orow[(tt - 1) * H] = h;   // h_{t-1} store fills the gap

        float ai = xgi, af = xgf, ag = xgg, ao = xgo;
#pragma unroll
        for (int q = 0; q < 4; ++q) {
            float4 h4 = *(const float4*)&hbuf[w][rl][q * 4];
            FMAC(ai, Wi[q * 4 + 0], h4.x);
            FMAC(af, Wf[q * 4 + 0], h4.x);
            FMAC(ag, Wg[q * 4 + 0], h4.x);
            FMAC(ao, Wo[q * 4 + 0], h4.x);
            FMAC(ai, Wi[q * 4 + 1], h4.y);
            FMAC(af, Wf[q * 4 + 1], h4.y);
            FMAC(ag, Wg[q * 4 + 1], h4.y);
            FMAC(ao, Wo[q * 4 + 1], h4.y);
            FMAC(ai, Wi[q * 4 + 2], h4.z);
            FMAC(af, Wf[q * 4 + 2], h4.z);
            FMAC(ag, Wg[q * 4 + 2], h4.z);
            FMAC(ao, Wo[q * 4 + 2], h4.z);
            FMAC(ai, Wi[q * 4 + 3], h4.w);
            FMAC(af, Wf[q * 4 + 3], h4.w);
            FMAC(ag, Wg[q * 4 + 3], h4.w);
            FMAC(ao, Wo[q * 4 + 3], h4.w);
        }
        {
            const float hk = hbuf[w][rl][16];
            FMAC(ai, Wi[16], hk);
            FMAC(af, Wf[16], hk);
            FMAC(ag, Wg[16], hk);
            FMAC(ao, Wo[16], hk);
        }

        const float ig = fsigmoid(ai);
        const float fg = fsigmoid(af);
        const float gv = ftanhf(ag);
        const float og = fsigmoid(ao);
        c = fmaf(fg, c, ig * gv);
        h = og * ftanhf(c);
    }
    if (valid) orow[(TSTEPS - 1) * H] = h;             // final delayed store
}

extern "C" void kernel_launch(void* const* d_in, const int* in_sizes, int n_in,
                              void* d_out, int out_size, void* d_ws, size_t ws_size,
                              hipStream_t stream)
{
    const float* x    = (const float*)d_in[0];
    const float* W_h0 = (const float*)d_in[1];
    const float* b_h0 = (const float*)d_in[2];
    const float* W_c0 = (const float*)d_in[3];
    const float* b_c0 = (const float*)d_in[4];
    const float* W_ih = (const float*)d_in[5];
    const float* W_hh = (const float*)d_in[6];
    const float* b_ih = (const float*)d_in[7];
    const float* b_hh = (const float*)d_in[8];
    float* out = (float*)d_out;

    (void)d_ws; (void)ws_size;  // no workspace used

    const int nblk = (BTOT + RPB - 1) / RPB;   // 1366
    hipLaunchKernelGGL(lstm_fused, dim3(nblk), dim3(TPB), 0, stream,
                       x, W_h0, b_h0, W_c0, b_c0, W_ih, W_hh, b_ih, b_hh, out);
}

// Round 12
// 493.092 us; speedup vs baseline: 1.2818x; 1.2818x over previous
//
#include <hip/hip_runtime.h>
#include <math.h>

#define BTOT   32768
#define LAT    128
#define H      17
#define G4     68      // 4*H
#define TSTEPS 50
#define NPR    102     // projection rows: 68 (W_ih) + 17 (W_h0) + 17 (W_c0)
#define NPRP   104
#define WPAD   72      // R8 layout: best measured conflicts (6.84M)

#define NW     8              // waves per block
#define RPW    3              // rows per wave (51 active lanes of 64)
#define RPB    (NW * RPW)     // 24 rows per block
#define TPB    (NW * 64)      // 512 threads

// R8 swizzle (best measured): byte-16 XOR keyed on row bit 3.
#define WSWZ(row, c4) ((c4) ^ ((((row) >> 3) & 1) << 2))

// fast gates: f32 only (R9: recurrence amplifies per-step error ~1e3x; f16 fails).
__device__ __forceinline__ float fsigmoid(float x) {
    float e = __expf(-x);
    return __builtin_amdgcn_rcpf(1.0f + e);
}
// tanh(x) = 1 - 2*rcp(exp(2x)+1); +inf -> 1, -inf -> -1, no divide.
__device__ __forceinline__ float ftanhf(float x) {
    float e = __expf(2.0f * x);
    float t = __builtin_amdgcn_rcpf(e + 1.0f);
    return fmaf(-2.0f, t, 1.0f);
}

#define FMAC(acc, w, h) asm("v_fmac_f32 %0, %1, %2" : "+v"(acc) : "v"(w), "v"(h))

__global__ __launch_bounds__(TPB, 4)
void lstm_fused(const float* __restrict__ x,
                const float* __restrict__ W_h0, const float* __restrict__ b_h0,
                const float* __restrict__ W_c0, const float* __restrict__ b_c0,
                const float* __restrict__ W_ih, const float* __restrict__ W_hh,
                const float* __restrict__ b_ih, const float* __restrict__ b_hh,
                float* __restrict__ out)
{
    __shared__ float x_tile[RPB][132];      // 12.7 KB
    __shared__ float Wbuf[NPR][WPAD];       // 29.4 KB (one k-half, R8 layout)
    __shared__ float Wl[G4 * H];            //  4.6 KB (W_hh f32)
    __shared__ float hbuf[NW][RPW][20];     //  1.9 KB (wave-private h rows)

    const int t    = threadIdx.x;
    const int w    = t >> 6;
    const int lane = t & 63;
    const bool active = lane < RPW * H;       // 51
    const int rl = active ? (lane / H) : 0;   // 0..2
    const int j  = active ? (lane % H) : 0;   // 0..16
    const int r  = w * RPW + rl;              // 0..23
    const int grow0 = blockIdx.x * RPB;
    int grow = grow0 + r;
    const bool valid = active && (grow < BTOT);
    if (grow >= BTOT) grow = BTOT - 1;

    // ---- stage x tile (rows clamped) + W_hh; all 512 threads ----
    for (int i = t; i < RPB * 32; i += TPB) {              // 32 float4 per row
        int rr = i >> 5, c = i & 31;
        int gr = grow0 + rr; if (gr >= BTOT) gr = BTOT - 1;
        *(float4*)&x_tile[rr][c * 4] = ((const float4*)(x + (size_t)gr * LAT))[c];
    }
    for (int i = t; i < G4 * H; i += TPB) Wl[i] = W_hh[i];

    // ---- phase 1: projections, two k-halves of 64 (R8 proven layout) ----
    float acc[6] = {0.f, 0.f, 0.f, 0.f, 0.f, 0.f};         // i,f,g,o, h0, c0
    const int rows6[6] = { j, 17 + j, 34 + j, 51 + j, 68 + j, 85 + j };
    for (int kh = 0; kh < 2; ++kh) {
        __syncthreads();  // kh=0: x_tile/Wl ready; kh=1: WAR on Wbuf
        for (int i = t; i < NPR * 16; i += TPB) {          // 16 float4 per half-row
            int row = i >> 4, c4 = (i & 15) * 4;
            const float* src = (row < G4) ? (W_ih + row * LAT)
                             : (row < 85) ? (W_h0 + (row - G4) * LAT)
                                          : (W_c0 + (row - 85) * LAT);
            *(float4*)&Wbuf[row][WSWZ(row, c4)] = *(const float4*)(src + kh * 64 + c4);
        }
        __syncthreads();  // half ready

        for (int kb = 0; kb < 16; ++kb) {
            float4 xv = *(const float4*)&x_tile[r][kh * 64 + kb * 4];
#pragma unroll
            for (int s = 0; s < 6; ++s) {
                const int row = rows6[s];
                float4 wv = *(const float4*)&Wbuf[row][WSWZ(row, kb * 4)];
                acc[s] = fmaf(xv.x, wv.x, acc[s]);
                acc[s] = fmaf(xv.y, wv.y, acc[s]);
                acc[s] = fmaf(xv.z, wv.z, acc[s]);
                acc[s] = fmaf(xv.w, wv.w, acc[s]);
            }
        }
    }

    // ---- DEPHASE (spill-safe): placed AFTER the last barrier, BEFORE the
    // W-register load so the live set is ~10 regs (R11 lesson: a switch with
    // W[68] live spilled to scratch, 848MB writes). Staggers co-resident
    // waves by 0/256/512/768 cyc so their per-step LDS stall windows overlap
    // neighbors' compute windows (zero-overlap theory: 10.7 waves/SIMD run
    // serially at ~450cyc/step = measured 100us T-loop; issue-bound is 42us).
    {
        int stag = (blockIdx.x ^ w) & 3;
        for (int i = 0; i < stag; ++i) __builtin_amdgcn_s_sleep(4);
    }

    const float xgi = acc[0] + b_ih[j]      + b_hh[j];
    const float xgf = acc[1] + b_ih[17 + j] + b_hh[17 + j];
    const float xgg = acc[2] + b_ih[34 + j] + b_hh[34 + j];
    const float xgo = acc[3] + b_ih[51 + j] + b_hh[51 + j];
    float h = acc[4] + b_h0[j];
    float c = acc[5] + b_c0[j];

    // ---- W_hh rows for gates i,f,g,o of element j -> registers ----
    float Wi[H], Wf[H], Wg[H], Wo[H];
#pragma unroll
    for (int k = 0; k < H; ++k) {
        Wi[k] = Wl[(0 * H + j) * H + k];
        Wf[k] = Wl[(1 * H + j) * H + k];
        Wg[k] = Wl[(2 * H + j) * H + k];
        Wo[k] = Wl[(3 * H + j) * H + k];
        asm volatile("" : "+v"(Wi[k]), "+v"(Wf[k]), "+v"(Wg[k]), "+v"(Wo[k]));
    }

    // ---- phase 2: 50-step recurrence, NO barriers (rows are wave-local) ----
    // Output store delayed one step so it issues inside the LDS wait window.
    float* orow = out + (size_t)grow * (TSTEPS * H) + j;
    for (int tt = 0; tt < TSTEPS; ++tt) {
        if (active) hbuf[w][rl][j] = h;
        if (valid && tt > 0) orow[(tt - 1) * H] = h;   // h_{t-1} store fills the gap

        float ai = xgi, af = xgf, ag = xgg, ao = xgo;
#pragma unroll
        for (int q = 0; q < 4; ++q) {
            float4 h4 = *(const float4*)&hbuf[w][rl][q * 4];
            FMAC(ai, Wi[q * 4 + 0], h4.x);
            FMAC(af, Wf[q * 4 + 0], h4.x);
            FMAC(ag, Wg[q * 4 + 0], h4.x);
            FMAC(ao, Wo[q * 4 + 0], h4.x);
            FMAC(ai, Wi[q * 4 + 1], h4.y);
            FMAC(af, Wf[q * 4 + 1], h4.y);
            FMAC(ag, Wg[q * 4 + 1], h4.y);
            FMAC(ao, Wo[q * 4 + 1], h4.y);
            FMAC(ai, Wi[q * 4 + 2], h4.z);
            FMAC(af, Wf[q * 4 + 2], h4.z);
            FMAC(ag, Wg[q * 4 + 2], h4.z);
            FMAC(ao, Wo[q * 4 + 2], h4.z);
            FMAC(ai, Wi[q * 4 + 3], h4.w);
            FMAC(af, Wf[q * 4 + 3], h4.w);
            FMAC(ag, Wg[q * 4 + 3], h4.w);
            FMAC(ao, Wo[q * 4 + 3], h4.w);
        }
        {
            const float hk = hbuf[w][rl][16];
            FMAC(ai, Wi[16], hk);
            FMAC(af, Wf[16], hk);
            FMAC(ag, Wg[16], hk);
            FMAC(ao, Wo[16], hk);
        }

        const float ig = fsigmoid(ai);
        const float fg = fsigmoid(af);
        const float gv = ftanhf(ag);
        const float og = fsigmoid(ao);
        c = fmaf(fg, c, ig * gv);
        h = og * ftanhf(c);
    }
    if (valid) orow[(TSTEPS - 1) * H] = h;             // final delayed store
}

extern "C" void kernel_launch(void* const* d_in, const int* in_sizes, int n_in,
                              void* d_out, int out_size, void* d_ws, size_t ws_size,
                              hipStream_t stream)
{
    const float* x    = (const float*)d_in[0];
    const float* W_h0 = (const float*)d_in[1];
    const float* b_h0 = (const float*)d_in[2];
    const float* W_c0 = (const float*)d_in[3];
    const float* b_c0 = (const float*)d_in[4];
    const float* W_ih = (const float*)d_in[5];
    const float* W_hh = (const float*)d_in[6];
    const float* b_ih = (const float*)d_in[7];
    const float* b_hh = (const float*)d_in[8];
    float* out = (float*)d_out;

    (void)d_ws; (void)ws_size;  // no workspace used

    const int nblk = (BTOT + RPB - 1) / RPB;   // 1366
    hipLaunchKernelGGL(lstm_fused, dim3(nblk), dim3(TPB), 0, stream,
                       x, W_h0, b_h0, W_c0, b_c0, W_ih, W_hh, b_ih, b_hh, out);
}

// Round 13
// 131.370 us; speedup vs baseline: 4.8112x; 3.7535x over previous
//
#include <hip/hip_runtime.h>
#include <math.h>

#define BTOT   32768
#define LAT    128
#define H      17
#define G4     68      // 4*H
#define TSTEPS 50
#define NPR    102     // projection rows: 68 (W_ih) + 17 (W_h0) + 17 (W_c0)
#define WPAD   72

#define NW     8              // waves per block
#define RPB    48             // 6 rows per wave (3 in set A, 3 in set B)
#define TPB    512

// x_tile stride 132: rows r,r+8,r+16 alias (1056 ≡ 0 mod 128B) -> 2-bit XOR key.
#define XSWZ(r, c4)   ((c4) ^ ((((r) >> 3) & 3) << 2))
// Wbuf stride 72: rows j,j+4,j+8,j+12 alias (288B ≡ 0 mod 128B) -> key on bits 2-3.
#define WSWZ(row, c4) ((c4) ^ ((((row) >> 2) & 3) << 2))

// f32-only gates (R9: recurrence amplifies per-step error ~1e3x; f16 fails).
__device__ __forceinline__ float fsigmoid(float x) {
    float e = __expf(-x);
    return __builtin_amdgcn_rcpf(1.0f + e);
}
// tanh(x) = 1 - 2*rcp(exp(2x)+1); +inf -> 1, -inf -> -1, no divide.
__device__ __forceinline__ float ftanhf(float x) {
    float e = __expf(2.0f * x);
    float t = __builtin_amdgcn_rcpf(e + 1.0f);
    return fmaf(-2.0f, t, 1.0f);
}

#define FMAC(acc, w, h) asm("v_fmac_f32 %0, %1, %2" : "+v"(acc) : "v"(w), "v"(h))

// (512,2): reg cap 256 -> structurally no spill (R11/R12: spill = catastrophe).
// Latency hiding comes from the A/B software pipeline (ILP), not occupancy.
__global__ __launch_bounds__(TPB, 2)
void lstm_fused(const float* __restrict__ x,
                const float* __restrict__ W_h0, const float* __restrict__ b_h0,
                const float* __restrict__ W_c0, const float* __restrict__ b_c0,
                const float* __restrict__ W_ih, const float* __restrict__ W_hh,
                const float* __restrict__ b_ih, const float* __restrict__ b_hh,
                float* __restrict__ out)
{
    __shared__ float x_tile[RPB][132];      // 25.3 KB (XOR-swizzled cols)
    __shared__ float Wbuf[NPR][WPAD];       // 29.4 KB (one k-half, XOR-swizzled)
    __shared__ float Wl[G4 * H];            //  4.6 KB (W_hh f32)
    __shared__ float hbuf[NW][6][20];       //  3.8 KB (6 wave-private h rows)
    // total 63.1 KB -> 2 blocks/CU by LDS

    const int t    = threadIdx.x;
    const int w    = t >> 6;
    const int lane = t & 63;
    const bool active = lane < 3 * H;         // 51
    const int rl = active ? (lane / H) : 0;   // 0..2
    const int j  = active ? (lane % H) : 0;   // 0..16
    const int rA = w * 6 + rl;                // set-A row (0..47 local)
    const int rB = rA + 3;                    // set-B row
    const int grow0 = blockIdx.x * RPB;
    int growA = grow0 + rA;
    int growB = grow0 + rB;
    const bool validA = active && (growA < BTOT);
    const bool validB = active && (growB < BTOT);
    if (growA >= BTOT) growA = BTOT - 1;
    if (growB >= BTOT) growB = BTOT - 1;

    // ---- stage x tile (rows clamped) + W_hh; all 512 threads ----
    for (int i = t; i < RPB * 32; i += TPB) {              // 32 float4 per row
        int rr = i >> 5, c4 = (i & 31) * 4;
        int gr = grow0 + rr; if (gr >= BTOT) gr = BTOT - 1;
        *(float4*)&x_tile[rr][XSWZ(rr, c4)] =
            *(const float4*)(x + (size_t)gr * LAT + c4);
    }
    for (int i = t; i < G4 * H; i += TPB) Wl[i] = W_hh[i];

    // ---- phase 1: projections for BOTH row-sets, two k-halves of 64 ----
    float acc[12];                                         // A: 0-5, B: 6-11
#pragma unroll
    for (int s = 0; s < 12; ++s) acc[s] = 0.0f;
    const int rows6[6] = { j, 17 + j, 34 + j, 51 + j, 68 + j, 85 + j };
    for (int kh = 0; kh < 2; ++kh) {
        __syncthreads();  // kh=0: x_tile/Wl ready; kh=1: WAR on Wbuf
        for (int i = t; i < NPR * 16; i += TPB) {          // 16 float4 per half-row
            int row = i >> 4, c4 = (i & 15) * 4;
            const float* src = (row < G4) ? (W_ih + row * LAT)
                             : (row < 85) ? (W_h0 + (row - G4) * LAT)
                                          : (W_c0 + (row - 85) * LAT);
            *(float4*)&Wbuf[row][WSWZ(row, c4)] = *(const float4*)(src + kh * 64 + c4);
        }
        __syncthreads();  // half ready

        for (int kb = 0; kb < 16; ++kb) {
            const int xc = kh * 64 + kb * 4;
            float4 xa = *(const float4*)&x_tile[rA][XSWZ(rA, xc)];
            float4 xb = *(const float4*)&x_tile[rB][XSWZ(rB, xc)];
#pragma unroll
            for (int s = 0; s < 6; ++s) {
                const int row = rows6[s];
                float4 wv = *(const float4*)&Wbuf[row][WSWZ(row, kb * 4)];
                acc[s]     = fmaf(xa.x, wv.x, acc[s]);
                acc[s]     = fmaf(xa.y, wv.y, acc[s]);
                acc[s]     = fmaf(xa.z, wv.z, acc[s]);
                acc[s]     = fmaf(xa.w, wv.w, acc[s]);
                acc[6 + s] = fmaf(xb.x, wv.x, acc[6 + s]);
                acc[6 + s] = fmaf(xb.y, wv.y, acc[6 + s]);
                acc[6 + s] = fmaf(xb.z, wv.z, acc[6 + s]);
                acc[6 + s] = fmaf(xb.w, wv.w, acc[6 + s]);
            }
        }
    }

    const float bi0 = b_ih[j]      + b_hh[j];
    const float bi1 = b_ih[17 + j] + b_hh[17 + j];
    const float bi2 = b_ih[34 + j] + b_hh[34 + j];
    const float bi3 = b_ih[51 + j] + b_hh[51 + j];
    const float xgAi = acc[0] + bi0, xgAf = acc[1] + bi1;
    const float xgAg = acc[2] + bi2, xgAo = acc[3] + bi3;
    const float xgBi = acc[6] + bi0, xgBf = acc[7] + bi1;
    const float xgBg = acc[8] + bi2, xgBo = acc[9] + bi3;
    float hA = acc[4]  + b_h0[j], cA = acc[5]  + b_c0[j];
    float hB = acc[10] + b_h0[j], cB = acc[11] + b_c0[j];

    // ---- W_hh rows for gates i,f,g,o of element j -> registers ----
    float Wi[H], Wf[H], Wg[H], Wo[H];
#pragma unroll
    for (int k = 0; k < H; ++k) {
        Wi[k] = Wl[(0 * H + j) * H + k];
        Wf[k] = Wl[(1 * H + j) * H + k];
        Wg[k] = Wl[(2 * H + j) * H + k];
        Wo[k] = Wl[(3 * H + j) * H + k];
        asm volatile("" : "+v"(Wi[k]), "+v"(Wf[k]), "+v"(Wg[k]), "+v"(Wo[k]));
    }

    // ---- phase 2: 2-stage A/B software pipeline, zero barriers ----
    // B's exchange issues at loop top, consumed at loop bottom (hidden under
    // A's compute). A's exchange issues mid-loop, consumed next iteration
    // (hidden under B's compute). Same-wave DS ops are in-order; the compiler
    // emits counted lgkmcnt before each consumer. No __syncthreads needed.
    float* orowA = out + (size_t)growA * (TSTEPS * H) + j;
    float* orowB = out + (size_t)growB * (TSTEPS * H) + j;
    const float* hbA = &hbuf[w][rl][0];
    const float* hbB = &hbuf[w][3 + rl][0];

    // prologue: A's step-0 exchange
    if (active) hbuf[w][rl][j] = hA;
    float4 a0 = *(const float4*)&hbA[0];
    float4 a1 = *(const float4*)&hbA[4];
    float4 a2 = *(const float4*)&hbA[8];
    float4 a3 = *(const float4*)&hbA[12];
    float  a4 = hbA[16];

    for (int tt = 0; tt < TSTEPS; ++tt) {
        // --- B exchange for this step (consumed below, after A's compute) ---
        if (active) hbuf[w][3 + rl][j] = hB;
        float4 b0 = *(const float4*)&hbB[0];
        float4 b1 = *(const float4*)&hbB[4];
        float4 b2 = *(const float4*)&hbB[8];
        float4 b3 = *(const float4*)&hbB[12];
        float  b4 = hbB[16];

        // --- A compute (reads a0..a4, issued last iteration / prologue) ---
        {
            float ai = xgAi, af = xgAf, ag = xgAg, ao = xgAo;
            float4 hq[4] = { a0, a1, a2, a3 };
#pragma unroll
            for (int q = 0; q < 4; ++q) {
                FMAC(ai, Wi[q * 4 + 0], hq[q].x); FMAC(af, Wf[q * 4 + 0], hq[q].x);
                FMAC(ag, Wg[q * 4 + 0], hq[q].x); FMAC(ao, Wo[q * 4 + 0], hq[q].x);
                FMAC(ai, Wi[q * 4 + 1], hq[q].y); FMAC(af, Wf[q * 4 + 1], hq[q].y);
                FMAC(ag, Wg[q * 4 + 1], hq[q].y); FMAC(ao, Wo[q * 4 + 1], hq[q].y);
                FMAC(ai, Wi[q * 4 + 2], hq[q].z); FMAC(af, Wf[q * 4 + 2], hq[q].z);
                FMAC(ag, Wg[q * 4 + 2], hq[q].z); FMAC(ao, Wo[q * 4 + 2], hq[q].z);
                FMAC(ai, Wi[q * 4 + 3], hq[q].w); FMAC(af, Wf[q * 4 + 3], hq[q].w);
                FMAC(ag, Wg[q * 4 + 3], hq[q].w); FMAC(ao, Wo[q * 4 + 3], hq[q].w);
            }
            FMAC(ai, Wi[16], a4); FMAC(af, Wf[16], a4);
            FMAC(ag, Wg[16], a4); FMAC(ao, Wo[16], a4);
            const float ig = fsigmoid(ai), fg = fsigmoid(af);
            const float gv = ftanhf(ag),  og = fsigmoid(ao);
            cA = fmaf(fg, cA, ig * gv);
            hA = og * ftanhf(cA);
        }

        // --- A exchange for NEXT step (hidden under B's compute) ---
        if (active) hbuf[w][rl][j] = hA;
        a0 = *(const float4*)&hbA[0];
        a1 = *(const float4*)&hbA[4];
        a2 = *(const float4*)&hbA[8];
        a3 = *(const float4*)&hbA[12];
        a4 = hbA[16];

        // --- B compute (reads b0..b4, issued at loop top) ---
        {
            float ai = xgBi, af = xgBf, ag = xgBg, ao = xgBo;
            float4 hq[4] = { b0, b1, b2, b3 };
#pragma unroll
            for (int q = 0; q < 4; ++q) {
                FMAC(ai, Wi[q * 4 + 0], hq[q].x); FMAC(af, Wf[q * 4 + 0], hq[q].x);
                FMAC(ag, Wg[q * 4 + 0], hq[q].x); FMAC(ao, Wo[q * 4 + 0], hq[q].x);
                FMAC(ai, Wi[q * 4 + 1], hq[q].y); FMAC(af, Wf[q * 4 + 1], hq[q].y);
                FMAC(ag, Wg[q * 4 + 1], hq[q].y); FMAC(ao, Wo[q * 4 + 1], hq[q].y);
                FMAC(ai, Wi[q * 4 + 2], hq[q].z); FMAC(af, Wf[q * 4 + 2], hq[q].z);
                FMAC(ag, Wg[q * 4 + 2], hq[q].z); FMAC(ao, Wo[q * 4 + 2], hq[q].z);
                FMAC(ai, Wi[q * 4 + 3], hq[q].w); FMAC(af, Wf[q * 4 + 3], hq[q].w);
                FMAC(ag, Wg[q * 4 + 3], hq[q].w); FMAC(ao, Wo[q * 4 + 3], hq[q].w);
            }
            FMAC(ai, Wi[16], b4); FMAC(af, Wf[16], b4);
            FMAC(ag, Wg[16], b4); FMAC(ao, Wo[16], b4);
            const float ig = fsigmoid(ai), fg = fsigmoid(af);
            const float gv = ftanhf(ag),  og = fsigmoid(ao);
            cB = fmaf(fg, cB, ig * gv);
            hB = og * ftanhf(cB);
        }

        // --- stores (async vmem, off the critical path) ---
        if (validA) orowA[tt * H] = hA;
        if (validB) orowB[tt * H] = hB;
    }
}

extern "C" void kernel_launch(void* const* d_in, const int* in_sizes, int n_in,
                              void* d_out, int out_size, void* d_ws, size_t ws_size,
                              hipStream_t stream)
{
    const float* x    = (const float*)d_in[0];
    const float* W_h0 = (const float*)d_in[1];
    const float* b_h0 = (const float*)d_in[2];
    const float* W_c0 = (const float*)d_in[3];
    const float* b_c0 = (const float*)d_in[4];
    const float* W_ih = (const float*)d_in[5];
    const float* W_hh = (const float*)d_in[6];
    const float* b_ih = (const float*)d_in[7];
    const float* b_hh = (const float*)d_in[8];
    float* out = (float*)d_out;

    (void)d_ws; (void)ws_size;  // no workspace used

    const int nblk = (BTOT + RPB - 1) / RPB;   // 683
    hipLaunchKernelGGL(lstm_fused, dim3(nblk), dim3(TPB), 0, stream,
                       x, W_h0, b_h0, W_c0, b_c0, W_ih, W_hh, b_ih, b_hh, out);
}